// Round 8
// baseline (278.501 us; speedup 1.0000x reference)
//
#include <hip/hip_runtime.h>
#include <stdint.h>

#define BT 128
#define NN 1024
#define FF 128

typedef __attribute__((ext_vector_type(8))) short short8;
typedef __attribute__((ext_vector_type(4))) float float4v;
typedef __attribute__((ext_vector_type(16))) float float16v;
typedef __attribute__((ext_vector_type(4))) unsigned short ushort4v;

__device__ __forceinline__ unsigned short f2bf(float f) {
  uint32_t u = __builtin_bit_cast(uint32_t, f);
  u += 0x7FFFu + ((u >> 16) & 1u);   // RNE
  return (unsigned short)(u >> 16);
}

__device__ __forceinline__ void gload16(const void* g, void* l) {
  __builtin_amdgcn_global_load_lds(
      (const __attribute__((address_space(1))) uint32_t*)(g),
      (__attribute__((address_space(3))) uint32_t*)(l),
      16, 0, 0);
}

// phase helpers: reads issued in phase p are consumed in phase p+1 -> wait
// lgkmcnt(6) retires the 6 old reads, leaves the 6 just-issued in flight.
__device__ __forceinline__ void ph_in6() {
  __builtin_amdgcn_s_barrier();
  asm volatile("s_waitcnt lgkmcnt(6)" ::: "memory");
  __builtin_amdgcn_sched_barrier(0);
  __builtin_amdgcn_s_setprio(1);
}
__device__ __forceinline__ void ph_in0() {
  __builtin_amdgcn_s_barrier();
  asm volatile("s_waitcnt lgkmcnt(0)" ::: "memory");
  __builtin_amdgcn_sched_barrier(0);
  __builtin_amdgcn_s_setprio(1);
}
__device__ __forceinline__ void ph_out() {
  __builtin_amdgcn_s_setprio(0);
  __builtin_amdgcn_sched_barrier(0);
  __builtin_amdgcn_s_barrier();
  __builtin_amdgcn_sched_barrier(0);
}

// ---- fused: S -> Sbf + SbfT (blocks 0..63); W -> Wk2 (blocks 64..319) ------
__global__ __launch_bounds__(256) void k_cvt_sw(const float* __restrict__ S,
                                                unsigned short* __restrict__ Sbf,
                                                unsigned short* __restrict__ SbfT,
                                                const float* __restrict__ W,
                                                unsigned short* __restrict__ Wk2) {
  __shared__ unsigned short tile[128 * 132];
  int tid = threadIdx.x;
  if (blockIdx.x >= 64) {
    int gid = (blockIdx.x - 64) * 256 + tid;
    int k = gid >> 14, o = (gid >> 7) & 127, f = gid & 127;
    Wk2[gid] = f2bf(W[(o * 128 + f) * 4 + k]);
    return;
  }
  int r0 = ((int)blockIdx.x >> 3) << 7;
  int c0 = ((int)blockIdx.x & 7) << 7;
#pragma unroll
  for (int i = 0; i < 16; ++i) {
    int idx = i * 256 + tid;          // 4096 float4s
    int r = idx >> 5, cq = idx & 31;
    float4v v = reinterpret_cast<const float4v*>(S)[(size_t)(r0 + r) * 256 + (c0 >> 2) + cq];
    ushort4v h;
    h[0] = f2bf(v[0]); h[1] = f2bf(v[1]); h[2] = f2bf(v[2]); h[3] = f2bf(v[3]);
    *reinterpret_cast<ushort4v*>(&Sbf[(size_t)(r0 + r) * 1024 + c0 + cq * 4]) = h;
    *reinterpret_cast<ushort4v*>(&tile[r * 132 + cq * 4]) = h;
  }
  __syncthreads();
#pragma unroll
  for (int i = 0; i < 16; ++i) {
    int idx = i * 256 + tid;          // 4096 packs
    int c = idx >> 5, rq = idx & 31;
    ushort4v h;
#pragma unroll
    for (int j = 0; j < 4; ++j) h[j] = tile[(rq * 4 + j) * 132 + c];
    *reinterpret_cast<ushort4v*>(&SbfT[(size_t)(c0 + c) * 1024 + r0 + rq * 4]) = h;
  }
}

// X fp32 [bt][n][f] -> Xbf bf16 same layout, Xt bf16 [bt][f][n]
__global__ __launch_bounds__(256) void k_cvt_x(const float* __restrict__ X,
                                               unsigned short* __restrict__ Xbf,
                                               unsigned short* __restrict__ Xt) {
  __shared__ unsigned short tile[128 * 132];
  int bt = blockIdx.x >> 3;
  int n0 = (blockIdx.x & 7) << 7;
  int tid = threadIdx.x;
  size_t base = ((size_t)bt * NN + n0) * FF;
#pragma unroll
  for (int i = 0; i < 16; ++i) {
    int idx = i * 256 + tid;
    int e = idx * 4;
    int n = e >> 7, f = e & 127;
    float4v v = reinterpret_cast<const float4v*>(X + base)[idx];
    ushort4v h;
    h[0] = f2bf(v[0]); h[1] = f2bf(v[1]); h[2] = f2bf(v[2]); h[3] = f2bf(v[3]);
    reinterpret_cast<ushort4v*>(Xbf + base)[idx] = h;
    *reinterpret_cast<ushort4v*>(&tile[n * 132 + f]) = h;
  }
  __syncthreads();
  size_t tbase = (size_t)bt * (FF * NN);
#pragma unroll
  for (int i = 0; i < 64; ++i) {
    int idx = i * 256 + tid;
    int f = idx >> 7, n = idx & 127;
    Xt[tbase + (size_t)f * NN + n0 + n] = tile[n * 132 + f];
  }
}

// ---- small 1024^3 GEMM (m97 structure): C[r][c] = sum_p A[r][p]*B[c][p] ----
__global__ __launch_bounds__(256) void gemm_s(const unsigned short* __restrict__ A,
                                              const unsigned short* __restrict__ B,
                                              unsigned short* __restrict__ C) {
  __shared__ unsigned short lA[128 * 64];
  __shared__ unsigned short lB[128 * 64];
  int r0 = ((int)blockIdx.x >> 3) << 7;
  int c0 = ((int)blockIdx.x & 7) << 7;
  int tid = threadIdx.x;
  int wave = tid >> 6, lane = tid & 63;
  int wr = wave >> 1, wc = wave & 1;
  int lr = lane & 15, g = lane >> 4;

  const unsigned short* gA = A + (size_t)r0 * 1024;
  const unsigned short* gB = B + (size_t)c0 * 1024;

  float4v acc[4][4];
#pragma unroll
  for (int a = 0; a < 4; ++a)
#pragma unroll
    for (int b = 0; b < 4; ++b) acc[a][b] = (float4v){0.f, 0.f, 0.f, 0.f};

  for (int kt = 0; kt < 16; ++kt) {
    int m0 = kt * 64;
#pragma unroll
    for (int i = 0; i < 4; ++i) {
      int id = i * 256 + tid;
      int row = id >> 3;
      int mc = (id & 7) << 3;
      int slot = (i * 256 + (tid & 192)) * 8;
      gload16(gA + (size_t)row * 1024 + m0 + mc, &lA[slot]);
      gload16(gB + (size_t)row * 1024 + m0 + mc, &lB[slot]);
    }
    __syncthreads();
#pragma unroll
    for (int kk = 0; kk < 2; ++kk) {
      short8 aF[4], bF[4];
#pragma unroll
      for (int mi = 0; mi < 4; ++mi)
        aF[mi] = *reinterpret_cast<const short8*>(
            &lA[(wr * 64 + mi * 16 + lr) * 64 + kk * 32 + g * 8]);
#pragma unroll
      for (int ni = 0; ni < 4; ++ni)
        bF[ni] = *reinterpret_cast<const short8*>(
            &lB[(wc * 64 + ni * 16 + lr) * 64 + kk * 32 + g * 8]);
#pragma unroll
      for (int mi = 0; mi < 4; ++mi)
#pragma unroll
        for (int ni = 0; ni < 4; ++ni)
          acc[mi][ni] = __builtin_amdgcn_mfma_f32_16x16x32_bf16(
              aF[mi], bF[ni], acc[mi][ni], 0, 0, 0);
    }
    __syncthreads();
  }

#pragma unroll
  for (int mi = 0; mi < 4; ++mi) {
#pragma unroll
    for (int ni = 0; ni < 4; ++ni) {
      int rr = r0 + wr * 64 + mi * 16 + g * 4;
      int cc = c0 + wc * 64 + ni * 16 + lr;
#pragma unroll
      for (int j = 0; j < 4; ++j)
        C[(size_t)(rr + j) * 1024 + cc] = f2bf(acc[mi][ni][j]);
    }
  }
}

// ---- batched chain GEMM, 256^2, 32x32x16 MFMA, kf-split pipelined phases ---
// Zn_k[bt][n][f] = sum_m Xt[(bt,f)][m] * S^k[n][m]
// Phase q: MFMA kf=q (frags read phase q-1) ; ds_read kf=q+1 into alt regs.
// lgkmcnt(6) per phase; stage 8 gload16 @q0 -> buf[nxt]; vmcnt(0) @q2 close.
__global__ __launch_bounds__(512, 2) void k_chain8(
    const unsigned short* __restrict__ Xt,
    const unsigned short* __restrict__ S1,
    const unsigned short* __restrict__ S2,
    const unsigned short* __restrict__ S3,
    unsigned short* __restrict__ Zn1,
    unsigned short* __restrict__ Zn2,
    unsigned short* __restrict__ Zn3) {
  extern __shared__ unsigned char lds[];   // 131072 B: 2 bufs x (A 32K + B 32K)

  int bid = blockIdx.x;
  int logical = (bid & 7) * 96 + (bid >> 3);     // 768 = 8 * 96 exact
  int cblk = logical / 12;
  int pkn = logical - cblk * 12;
  int power = pkn >> 2, nblk = pkn & 3;
  const unsigned short* Sp = (power == 0) ? S1 : ((power == 1) ? S2 : S3);
  unsigned short* Zn = (power == 0) ? Zn1 : ((power == 1) ? Zn2 : Zn3);

  int tid = threadIdx.x;
  int wave = tid >> 6, lane = tid & 63;
  int wave_m = wave >> 2, wave_n = wave & 3;
  int lo = lane & 31, hi = lane >> 5;

  // staging: wave w stages A-tile w and B-tile w, chunks j = kf 0..3.
  // LDS chunk (tile,kf) = 1KB lane-linear; dest uniform per wave (rule #21 ok).
  unsigned sA[4], sB[4], dA[4], dB[4];
#pragma unroll
  for (int j = 0; j < 4; ++j) {
    sA[j] = (unsigned)(cblk * 256 + wave * 32 + lo) * 1024u + (unsigned)(j * 16 + hi * 8);
    sB[j] = (unsigned)(nblk * 256 + wave * 32 + lo) * 1024u + (unsigned)(j * 16 + hi * 8);
    dA[j] = (unsigned)(wave * 4 + j) * 1024u;
    dB[j] = 32768u + (unsigned)(wave * 4 + j) * 1024u;
  }

  // ds_read bases (bytes): frag addr = base + sub*4096 + kf*1024 (+ lane*16)
  const unsigned aoff = (unsigned)wave_m * 16384u + (unsigned)(lane << 4);
  const unsigned boff = 32768u + (unsigned)wave_n * 8192u + (unsigned)(lane << 4);

#define RD6(aX, bX, BB, KF)                                               \
  {                                                                       \
    _Pragma("unroll") for (int a = 0; a < 4; ++a)                         \
        aX[a] = *reinterpret_cast<const short8*>(                         \
            lds + (BB) + aoff + (unsigned)(a)*4096u + (KF)*1024u);        \
    _Pragma("unroll") for (int b2 = 0; b2 < 2; ++b2)                      \
        bX[b2] = *reinterpret_cast<const short8*>(                        \
            lds + (BB) + boff + (unsigned)(b2)*4096u + (KF)*1024u);       \
  }

#define MFMA8(aX, bX)                                                     \
  {                                                                       \
    _Pragma("unroll") for (int a = 0; a < 4; ++a) {                       \
      acc[a][0] = __builtin_amdgcn_mfma_f32_32x32x16_bf16(                \
          aX[a], bX[0], acc[a][0], 0, 0, 0);                              \
      acc[a][1] = __builtin_amdgcn_mfma_f32_32x32x16_bf16(                \
          aX[a], bX[1], acc[a][1], 0, 0, 0);                              \
    }                                                                     \
  }

#define STAGE8(KO, NBO)                                                   \
  {                                                                       \
    _Pragma("unroll") for (int j = 0; j < 4; ++j) {                       \
      gload16(Xt + sA[j] + (KO), lds + (NBO) + dA[j]);                    \
      gload16(Sp + sB[j] + (KO), lds + (NBO) + dB[j]);                    \
    }                                                                     \
  }

  float16v acc[4][2];
#pragma unroll
  for (int a = 0; a < 4; ++a)
#pragma unroll
    for (int nt = 0; nt < 2; ++nt)
#pragma unroll
      for (int e = 0; e < 16; ++e) acc[a][nt][e] = 0.f;

  short8 aE[4], bE[2], aO[4], bO[2];

  // ---- prologue: stage kt=0 into buf0; read E(kf0)
  STAGE8(0u, 0u);
  asm volatile("s_waitcnt vmcnt(0)" ::: "memory");
  __builtin_amdgcn_s_barrier();
  RD6(aE, bE, 0u, 0u);

  for (int kt = 0; kt < 16; ++kt) {
    const unsigned bo = (unsigned)(kt & 1) << 16;
    const unsigned nbo = bo ^ 65536u;
    const unsigned ko = (unsigned)(kt + 1) * 64u;
    const bool st = (kt < 15);

    // q0: read O(kf1); stage kt+1; MFMA E(kf0)
    RD6(aO, bO, bo, 1u);
    if (st) STAGE8(ko, nbo);
    ph_in6();
    MFMA8(aE, bE);
    ph_out();

    // q1: read E(kf2); MFMA O(kf1)
    RD6(aE, bE, bo, 2u);
    ph_in6();
    MFMA8(aO, bO);
    ph_out();

    // q2: read O(kf3); MFMA E(kf2); vmcnt(0) before closing barrier
    RD6(aO, bO, bo, 3u);
    ph_in6();
    MFMA8(aE, bE);
    __builtin_amdgcn_s_setprio(0);
    __builtin_amdgcn_sched_barrier(0);
    if (st) asm volatile("s_waitcnt vmcnt(0)" ::: "memory");  // kt+1 staged
    __builtin_amdgcn_s_barrier();
    __builtin_amdgcn_sched_barrier(0);

    // q3: read E(kf0 of kt+1, other buf); MFMA O(kf3)
    if (st) {
      RD6(aE, bE, nbo, 0u);
      ph_in6();
    } else {
      ph_in0();
    }
    MFMA8(aO, bO);
    ph_out();
  }
#undef RD6
#undef MFMA8
#undef STAGE8

  // ---- epilogue (R5/R7-verified): bt = cblk*2 + wave_m, f = a*32 + rq*8 + hi*4
  int bt = cblk * 2 + wave_m;
  size_t zbase = (size_t)bt * (NN * FF);
  int n = nblk * 256 + wave_n * 64 + lo;
#pragma unroll
  for (int a = 0; a < 4; ++a) {
#pragma unroll
    for (int nt = 0; nt < 2; ++nt) {
      size_t rowb = zbase + (size_t)(n + nt * 32) * FF;
#pragma unroll
      for (int rq = 0; rq < 4; ++rq) {
        int f = a * 32 + rq * 8 + hi * 4;
        ushort4v pk;
#pragma unroll
        for (int j = 0; j < 4; ++j) pk[j] = f2bf(acc[a][nt][rq * 4 + j]);
        *reinterpret_cast<ushort4v*>(&Zn[rowb + f]) = pk;
      }
    }
  }
}

// ---- output GEMM: Y[bt][n][o] = sum_k sum_f Z_k[bt-k][n][f] * Wk2[k][o][f] + b
__global__ __launch_bounds__(256) void k_out(const unsigned short* __restrict__ Xbf,
                                             const unsigned short* __restrict__ Zn1,
                                             const unsigned short* __restrict__ Zn2,
                                             const unsigned short* __restrict__ Zn3,
                                             const unsigned short* __restrict__ Wk2,
                                             const float* __restrict__ bias,
                                             float* __restrict__ Y) {
  __shared__ unsigned short lA[128 * 64];
  __shared__ unsigned short lB[128 * 64];
  int bid = blockIdx.x;
  int bt = bid >> 3;
  int n0 = (bid & 7) << 7;
  int t = bt & 31;
  int tid = threadIdx.x;
  int wave = tid >> 6, lane = tid & 63;
  int wr = wave >> 1, wc = wave & 1;
  int lr = lane & 15, g = lane >> 4;

  const unsigned short* Zs[4] = {Xbf, Zn1, Zn2, Zn3};

  float4v acc[4][4];
#pragma unroll
  for (int a = 0; a < 4; ++a)
#pragma unroll
    for (int b = 0; b < 4; ++b) acc[a][b] = (float4v){0.f, 0.f, 0.f, 0.f};

  for (int s = 0; s < 8; ++s) {
    int k = s >> 1;
    if (t < k) break;
    int fh = (s & 1) * 64;
    const unsigned short* gA = Zs[k] + ((size_t)(bt - k) * NN + n0) * FF;
    const unsigned short* gB = Wk2 + k * (FF * FF);
#pragma unroll
    for (int i = 0; i < 4; ++i) {
      int id = i * 256 + tid;
      int row = id >> 3;
      int fc = (id & 7) << 3;
      int slot = (i * 256 + (tid & 192)) * 8;
      gload16(gA + (size_t)row * FF + fh + fc, &lA[slot]);
      gload16(gB + (size_t)row * FF + fh + fc, &lB[slot]);
    }
    __syncthreads();
#pragma unroll
    for (int kk = 0; kk < 2; ++kk) {
      short8 aF[4], bF[4];
#pragma unroll
      for (int mi = 0; mi < 4; ++mi)
        aF[mi] = *reinterpret_cast<const short8*>(
            &lA[(wr * 64 + mi * 16 + lr) * 64 + kk * 32 + g * 8]);
#pragma unroll
      for (int ni = 0; ni < 4; ++ni)
        bF[ni] = *reinterpret_cast<const short8*>(
            &lB[(wc * 64 + ni * 16 + lr) * 64 + kk * 32 + g * 8]);
#pragma unroll
      for (int mi = 0; mi < 4; ++mi)
#pragma unroll
        for (int ni = 0; ni < 4; ++ni)
          acc[mi][ni] = __builtin_amdgcn_mfma_f32_16x16x32_bf16(
              aF[mi], bF[ni], acc[mi][ni], 0, 0, 0);
    }
    __syncthreads();
  }

  size_t obase = (size_t)bt * (NN * FF);
#pragma unroll
  for (int mi = 0; mi < 4; ++mi) {
#pragma unroll
    for (int ni = 0; ni < 4; ++ni) {
      int nloc = n0 + wr * 64 + mi * 16 + g * 4;
      int o = wc * 64 + ni * 16 + lr;
      float bv = bias[o];
#pragma unroll
      for (int j = 0; j < 4; ++j)
        Y[obase + (size_t)(nloc + j) * FF + o] = acc[mi][ni][j] + bv;
    }
  }
}

// ---- launch ----------------------------------------------------------------

extern "C" void kernel_launch(void* const* d_in, const int* in_sizes, int n_in,
                              void* d_out, int out_size, void* d_ws, size_t ws_size,
                              hipStream_t stream) {
  const float* X = (const float*)d_in[0];
  const float* S = (const float*)d_in[1];
  const float* W = (const float*)d_in[2];
  const float* bvec = (const float*)d_in[3];
  float* Y = (float*)d_out;

  char* ws = (char*)d_ws;
  const size_t ZB = (size_t)BT * NN * FF * sizeof(unsigned short);  // 32 MiB
  const size_t SB = (size_t)1024 * 1024 * sizeof(unsigned short);   // 2 MiB
  unsigned short* Xt   = (unsigned short*)(ws + 0 * ZB);
  unsigned short* Zn1  = (unsigned short*)(ws + 1 * ZB);
  unsigned short* Zn2  = (unsigned short*)(ws + 2 * ZB);
  unsigned short* Zn3  = (unsigned short*)(ws + 3 * ZB);
  unsigned short* Xbf  = (unsigned short*)(ws + 4 * ZB);
  unsigned short* Sbf  = (unsigned short*)(ws + 5 * ZB);
  unsigned short* SbfT = (unsigned short*)(ws + 5 * ZB + 1 * SB);
  unsigned short* S2   = (unsigned short*)(ws + 5 * ZB + 2 * SB);
  unsigned short* S3   = (unsigned short*)(ws + 5 * ZB + 3 * SB);
  unsigned short* Wk2  = (unsigned short*)(ws + 5 * ZB + 4 * SB);

  k_cvt_sw<<<dim3(320), dim3(256), 0, stream>>>(S, Sbf, SbfT, W, Wk2);
  k_cvt_x<<<dim3(1024), dim3(256), 0, stream>>>(X, Xbf, Xt);

  gemm_s<<<dim3(64), dim3(256), 0, stream>>>(Sbf, SbfT, S2);   // S^2
  gemm_s<<<dim3(64), dim3(256), 0, stream>>>(S2, SbfT, S3);    // S^3

  hipError_t _e = hipFuncSetAttribute((const void*)k_chain8,
                      hipFuncAttributeMaxDynamicSharedMemorySize, 131072);
  (void)_e;
  k_chain8<<<dim3(768), dim3(512), 131072, stream>>>(Xt, Sbf, S2, S3, Zn1, Zn2, Zn3);

  k_out<<<dim3(1024), dim3(256), 0, stream>>>(Xbf, Zn1, Zn2, Zn3, Wk2, bvec, Y);
}

// Round 9
// 220.413 us; speedup vs baseline: 1.2635x; 1.2635x over previous
//
#include <hip/hip_runtime.h>
#include <stdint.h>

#define BT 128
#define NN 1024
#define FF 128

typedef __attribute__((ext_vector_type(8))) short short8;
typedef __attribute__((ext_vector_type(4))) float float4v;
typedef __attribute__((ext_vector_type(4))) unsigned short ushort4v;

__device__ __forceinline__ unsigned short f2bf(float f) {
  uint32_t u = __builtin_bit_cast(uint32_t, f);
  u += 0x7FFFu + ((u >> 16) & 1u);   // RNE
  return (unsigned short)(u >> 16);
}

__device__ __forceinline__ void gload16(const void* g, void* l) {
  __builtin_amdgcn_global_load_lds(
      (const __attribute__((address_space(1))) uint32_t*)(g),
      (__attribute__((address_space(3))) uint32_t*)(l),
      16, 0, 0);
}

// ---- fused: S -> Sbf + SbfT (blocks 0..63); W -> Wk2 (blocks 64..319) ------
__global__ __launch_bounds__(256) void k_cvt_sw(const float* __restrict__ S,
                                                unsigned short* __restrict__ Sbf,
                                                unsigned short* __restrict__ SbfT,
                                                const float* __restrict__ W,
                                                unsigned short* __restrict__ Wk2) {
  __shared__ unsigned short tile[128 * 132];
  int tid = threadIdx.x;
  if (blockIdx.x >= 64) {
    int gid = (blockIdx.x - 64) * 256 + tid;
    int k = gid >> 14, o = (gid >> 7) & 127, f = gid & 127;
    Wk2[gid] = f2bf(W[(o * 128 + f) * 4 + k]);
    return;
  }
  int r0 = ((int)blockIdx.x >> 3) << 7;
  int c0 = ((int)blockIdx.x & 7) << 7;
#pragma unroll
  for (int i = 0; i < 16; ++i) {
    int idx = i * 256 + tid;          // 4096 float4s
    int r = idx >> 5, cq = idx & 31;
    float4v v = reinterpret_cast<const float4v*>(S)[(size_t)(r0 + r) * 256 + (c0 >> 2) + cq];
    ushort4v h;
    h[0] = f2bf(v[0]); h[1] = f2bf(v[1]); h[2] = f2bf(v[2]); h[3] = f2bf(v[3]);
    *reinterpret_cast<ushort4v*>(&Sbf[(size_t)(r0 + r) * 1024 + c0 + cq * 4]) = h;
    *reinterpret_cast<ushort4v*>(&tile[r * 132 + cq * 4]) = h;
  }
  __syncthreads();
#pragma unroll
  for (int i = 0; i < 16; ++i) {
    int idx = i * 256 + tid;          // 4096 packs
    int c = idx >> 5, rq = idx & 31;
    ushort4v h;
#pragma unroll
    for (int j = 0; j < 4; ++j) h[j] = tile[(rq * 4 + j) * 132 + c];
    *reinterpret_cast<ushort4v*>(&SbfT[(size_t)(c0 + c) * 1024 + r0 + rq * 4]) = h;
  }
}

// X fp32 [bt][n][f] -> Xbf bf16 same layout, Xt bf16 [bt][f][n]
__global__ __launch_bounds__(256) void k_cvt_x(const float* __restrict__ X,
                                               unsigned short* __restrict__ Xbf,
                                               unsigned short* __restrict__ Xt) {
  __shared__ unsigned short tile[128 * 132];
  int bt = blockIdx.x >> 3;
  int n0 = (blockIdx.x & 7) << 7;
  int tid = threadIdx.x;
  size_t base = ((size_t)bt * NN + n0) * FF;
#pragma unroll
  for (int i = 0; i < 16; ++i) {
    int idx = i * 256 + tid;
    int e = idx * 4;
    int n = e >> 7, f = e & 127;
    float4v v = reinterpret_cast<const float4v*>(X + base)[idx];
    ushort4v h;
    h[0] = f2bf(v[0]); h[1] = f2bf(v[1]); h[2] = f2bf(v[2]); h[3] = f2bf(v[3]);
    reinterpret_cast<ushort4v*>(Xbf + base)[idx] = h;
    *reinterpret_cast<ushort4v*>(&tile[n * 132 + f]) = h;
  }
  __syncthreads();
  size_t tbase = (size_t)bt * (FF * NN);
#pragma unroll
  for (int i = 0; i < 64; ++i) {
    int idx = i * 256 + tid;
    int f = idx >> 7, n = idx & 127;
    Xt[tbase + (size_t)f * NN + n0 + n] = tile[n * 132 + f];
  }
}

// ---- small 1024^3 GEMM (m97 structure): C[r][c] = sum_p A[r][p]*B[c][p] ----
__global__ __launch_bounds__(256) void gemm_s(const unsigned short* __restrict__ A,
                                              const unsigned short* __restrict__ B,
                                              unsigned short* __restrict__ C) {
  __shared__ unsigned short lA[128 * 64];
  __shared__ unsigned short lB[128 * 64];
  int r0 = ((int)blockIdx.x >> 3) << 7;
  int c0 = ((int)blockIdx.x & 7) << 7;
  int tid = threadIdx.x;
  int wave = tid >> 6, lane = tid & 63;
  int wr = wave >> 1, wc = wave & 1;
  int lr = lane & 15, g = lane >> 4;

  const unsigned short* gA = A + (size_t)r0 * 1024;
  const unsigned short* gB = B + (size_t)c0 * 1024;

  float4v acc[4][4];
#pragma unroll
  for (int a = 0; a < 4; ++a)
#pragma unroll
    for (int b = 0; b < 4; ++b) acc[a][b] = (float4v){0.f, 0.f, 0.f, 0.f};

  for (int kt = 0; kt < 16; ++kt) {
    int m0 = kt * 64;
#pragma unroll
    for (int i = 0; i < 4; ++i) {
      int id = i * 256 + tid;
      int row = id >> 3;
      int mc = (id & 7) << 3;
      int slot = (i * 256 + (tid & 192)) * 8;
      gload16(gA + (size_t)row * 1024 + m0 + mc, &lA[slot]);
      gload16(gB + (size_t)row * 1024 + m0 + mc, &lB[slot]);
    }
    __syncthreads();
#pragma unroll
    for (int kk = 0; kk < 2; ++kk) {
      short8 aF[4], bF[4];
#pragma unroll
      for (int mi = 0; mi < 4; ++mi)
        aF[mi] = *reinterpret_cast<const short8*>(
            &lA[(wr * 64 + mi * 16 + lr) * 64 + kk * 32 + g * 8]);
#pragma unroll
      for (int ni = 0; ni < 4; ++ni)
        bF[ni] = *reinterpret_cast<const short8*>(
            &lB[(wc * 64 + ni * 16 + lr) * 64 + kk * 32 + g * 8]);
#pragma unroll
      for (int mi = 0; mi < 4; ++mi)
#pragma unroll
        for (int ni = 0; ni < 4; ++ni)
          acc[mi][ni] = __builtin_amdgcn_mfma_f32_16x16x32_bf16(
              aF[mi], bF[ni], acc[mi][ni], 0, 0, 0);
    }
    __syncthreads();
  }

#pragma unroll
  for (int mi = 0; mi < 4; ++mi) {
#pragma unroll
    for (int ni = 0; ni < 4; ++ni) {
      int rr = r0 + wr * 64 + mi * 16 + g * 4;
      int cc = c0 + wc * 64 + ni * 16 + lr;
#pragma unroll
      for (int j = 0; j < 4; ++j)
        C[(size_t)(rr + j) * 1024 + cc] = f2bf(acc[mi][ni][j]);
    }
  }
}

// ---- batched chain GEMM, 256^2, m201-faithful 4-phase quadrant schedule ----
// Zn_k[bt][n][f] = sum_m Xt[(bt,f)][m] * S^k[n][m]
// LDS: [256 row][64 k] row-major (128 B rows), XOR-swizzled k-segments
// (seg' = seg ^ (row&7)) via pre-swizzled coalesced global source (8 rows x
// 128 B per gload16 = 8 cache lines). Double buffer 2 x 64 KB.
// Stage-sets for kt+1 (16 KB = 2 gload16/wave): p0->SA0{rows 0-63,128-191},
// p1->SB0{0-31,64-95,128-159,192-223}, p2->SB1{+32}, p3->SA1{+64}.
// Quadrants: p0=(mh0,nh0) needs SA0+SB0, p1=(mh0,nh1) needs SB1,
// p2=(mh1,nh0) needs SA1, p3=(mh1,nh1). Counted vmcnt(4) at p0/p1/p3.
__global__ __launch_bounds__(512, 2) void k_chain8(
    const unsigned short* __restrict__ Xt,
    const unsigned short* __restrict__ S1,
    const unsigned short* __restrict__ S2,
    const unsigned short* __restrict__ S3,
    unsigned short* __restrict__ Zn1,
    unsigned short* __restrict__ Zn2,
    unsigned short* __restrict__ Zn3) {
  extern __shared__ unsigned char lds[];   // 131072 B

  int bid = blockIdx.x;
  int logical = (bid & 7) * 96 + (bid >> 3);     // 768 = 8 * 96 exact
  int cblk = logical / 12;
  int pkn = logical - cblk * 12;
  int power = pkn >> 2, nblk = pkn & 3;
  const unsigned short* Sp = (power == 0) ? S1 : ((power == 1) ? S2 : S3);
  unsigned short* Zn = (power == 0) ? Zn1 : ((power == 1) ? Zn2 : Zn3);

  int tid = threadIdx.x;
  int wave = tid >> 6, lane = tid & 63;
  int wave_m = wave >> 2, wave_n = wave & 3;
  int lr = lane & 15, g = lane >> 4;

  // ---- staging constants: sets 0=SA0, 1=SB0, 2=SB1, 3=SA1; 2 instr each.
  unsigned srcO[4][2], dstO[4][2];
#pragma unroll
  for (int j = 0; j < 2; ++j) {
    int sr0 = wave * 16 + j * 8;                       // multiple of 8
    int rbA = (sr0 & 63) + ((sr0 >> 6) << 7);          // A-set row base
    int rbB = (sr0 & 31) + ((sr0 >> 5) << 6);          // B-set row base
    int seg = lane & 7;
    int rA0 = rbA + (lane >> 3), rA1 = rA0 + 64;
    int rB0 = rbB + (lane >> 3), rB1 = rB0 + 32;
    srcO[0][j] = (unsigned)(cblk * 256 + rA0) * 1024u + (unsigned)((seg ^ (rA0 & 7)) << 3);
    srcO[3][j] = (unsigned)(cblk * 256 + rA1) * 1024u + (unsigned)((seg ^ (rA1 & 7)) << 3);
    srcO[1][j] = (unsigned)(nblk * 256 + rB0) * 1024u + (unsigned)((seg ^ (rB0 & 7)) << 3);
    srcO[2][j] = (unsigned)(nblk * 256 + rB1) * 1024u + (unsigned)((seg ^ (rB1 & 7)) << 3);
    dstO[0][j] = (unsigned)rbA * 128u;                 // wave-uniform
    dstO[3][j] = (unsigned)(rbA + 64) * 128u;
    dstO[1][j] = 32768u + (unsigned)rbB * 128u;
    dstO[2][j] = 32768u + (unsigned)(rbB + 32) * 128u;
  }

  // ---- ds_read constants (R3-verified swizzled frag reads)
  const unsigned xm = (unsigned)((lr & 7) << 4);
  const unsigned xo0 = ((unsigned)(g * 16)) ^ xm;
  const unsigned xo1 = ((unsigned)(64 + g * 16)) ^ xm;
  const unsigned aRB = (unsigned)((wave_m * 128 + lr) * 128);
  const unsigned bRB = 32768u + (unsigned)((wave_n * 64 + lr) * 128);

#define RD(OFF) (*reinterpret_cast<const short8*>(lds + (OFF)))

  float4v acc[8][4];
#pragma unroll
  for (int a = 0; a < 8; ++a)
#pragma unroll
    for (int b = 0; b < 4; ++b) acc[a][b] = (float4v){0.f, 0.f, 0.f, 0.f};

  short8 aF[4][2], bF[2][2], cF[2][2];

  // ---- prologue: stage kt0 (all sets) into buf0; drain; barrier
#pragma unroll
  for (int j = 0; j < 2; ++j) gload16(Xt + srcO[0][j], lds + dstO[0][j]);
#pragma unroll
  for (int j = 0; j < 2; ++j) gload16(Sp + srcO[1][j], lds + dstO[1][j]);
#pragma unroll
  for (int j = 0; j < 2; ++j) gload16(Sp + srcO[2][j], lds + dstO[2][j]);
#pragma unroll
  for (int j = 0; j < 2; ++j) gload16(Xt + srcO[3][j], lds + dstO[3][j]);
  asm volatile("s_waitcnt vmcnt(0)" ::: "memory");
  __builtin_amdgcn_s_barrier();

  for (int kt = 0; kt < 16; ++kt) {
    const unsigned bo = (unsigned)(kt & 1) << 16;
    const unsigned nbo = bo ^ 65536u;
    const unsigned ko = (unsigned)(kt + 1) * 64u;
    const bool st = (kt < 15);

    // ========== p0: 12 reads (aF mh0, bF nh0); stage SA0'; lgkm8; vmcnt ====
#pragma unroll
    for (int mf = 0; mf < 4; ++mf) {
      aF[mf][0] = RD(bo + aRB + (unsigned)mf * 2048u + xo0);
      aF[mf][1] = RD(bo + aRB + (unsigned)mf * 2048u + xo1);
    }
#pragma unroll
    for (int nf = 0; nf < 2; ++nf) {
      bF[nf][0] = RD(bo + bRB + (unsigned)nf * 2048u + xo0);
      bF[nf][1] = RD(bo + bRB + (unsigned)nf * 2048u + xo1);
    }
    if (st) {
      gload16(Xt + srcO[0][0] + ko, lds + nbo + dstO[0][0]);
      gload16(Xt + srcO[0][1] + ko, lds + nbo + dstO[0][1]);
      asm volatile("s_waitcnt lgkmcnt(8) vmcnt(4)" ::: "memory");
    } else {
      asm volatile("s_waitcnt lgkmcnt(8) vmcnt(2)" ::: "memory");
    }
    __builtin_amdgcn_s_barrier();
    asm volatile("s_waitcnt lgkmcnt(0)" ::: "memory");
    __builtin_amdgcn_sched_barrier(0);
    __builtin_amdgcn_s_setprio(1);
#pragma unroll
    for (int mf = 0; mf < 4; ++mf)
#pragma unroll
      for (int nf = 0; nf < 2; ++nf) {
        acc[mf][nf] = __builtin_amdgcn_mfma_f32_16x16x32_bf16(aF[mf][0], bF[nf][0], acc[mf][nf], 0, 0, 0);
        acc[mf][nf] = __builtin_amdgcn_mfma_f32_16x16x32_bf16(aF[mf][1], bF[nf][1], acc[mf][nf], 0, 0, 0);
      }
    __builtin_amdgcn_s_setprio(0);
    __builtin_amdgcn_sched_barrier(0);
    __builtin_amdgcn_s_barrier();
    __builtin_amdgcn_sched_barrier(0);

    // ========== p1: 4 reads (cF nh1); stage SB0'; vmcnt =====================
#pragma unroll
    for (int nf = 0; nf < 2; ++nf) {
      cF[nf][0] = RD(bo + bRB + 4096u + (unsigned)nf * 2048u + xo0);
      cF[nf][1] = RD(bo + bRB + 4096u + (unsigned)nf * 2048u + xo1);
    }
    if (st) {
      gload16(Sp + srcO[1][0] + ko, lds + nbo + dstO[1][0]);
      gload16(Sp + srcO[1][1] + ko, lds + nbo + dstO[1][1]);
      asm volatile("s_waitcnt vmcnt(4)" ::: "memory");
    } else {
      asm volatile("s_waitcnt vmcnt(0)" ::: "memory");
    }
    __builtin_amdgcn_s_barrier();
    asm volatile("s_waitcnt lgkmcnt(0)" ::: "memory");
    __builtin_amdgcn_sched_barrier(0);
    __builtin_amdgcn_s_setprio(1);
#pragma unroll
    for (int mf = 0; mf < 4; ++mf)
#pragma unroll
      for (int nf = 0; nf < 2; ++nf) {
        acc[mf][2 + nf] = __builtin_amdgcn_mfma_f32_16x16x32_bf16(aF[mf][0], cF[nf][0], acc[mf][2 + nf], 0, 0, 0);
        acc[mf][2 + nf] = __builtin_amdgcn_mfma_f32_16x16x32_bf16(aF[mf][1], cF[nf][1], acc[mf][2 + nf], 0, 0, 0);
      }
    __builtin_amdgcn_s_setprio(0);
    __builtin_amdgcn_sched_barrier(0);
    __builtin_amdgcn_s_barrier();
    __builtin_amdgcn_sched_barrier(0);

    // ========== p2: 8 reads (aF mh1); stage SB1'; no vm wait ================
#pragma unroll
    for (int mf = 0; mf < 4; ++mf) {
      aF[mf][0] = RD(bo + aRB + 8192u + (unsigned)mf * 2048u + xo0);
      aF[mf][1] = RD(bo + aRB + 8192u + (unsigned)mf * 2048u + xo1);
    }
    if (st) {
      gload16(Sp + srcO[2][0] + ko, lds + nbo + dstO[2][0]);
      gload16(Sp + srcO[2][1] + ko, lds + nbo + dstO[2][1]);
    }
    __builtin_amdgcn_s_barrier();
    asm volatile("s_waitcnt lgkmcnt(0)" ::: "memory");
    __builtin_amdgcn_sched_barrier(0);
    __builtin_amdgcn_s_setprio(1);
#pragma unroll
    for (int mf = 0; mf < 4; ++mf)
#pragma unroll
      for (int nf = 0; nf < 2; ++nf) {
        acc[4 + mf][nf] = __builtin_amdgcn_mfma_f32_16x16x32_bf16(aF[mf][0], bF[nf][0], acc[4 + mf][nf], 0, 0, 0);
        acc[4 + mf][nf] = __builtin_amdgcn_mfma_f32_16x16x32_bf16(aF[mf][1], bF[nf][1], acc[4 + mf][nf], 0, 0, 0);
      }
    __builtin_amdgcn_s_setprio(0);
    __builtin_amdgcn_sched_barrier(0);
    __builtin_amdgcn_s_barrier();
    __builtin_amdgcn_sched_barrier(0);

    // ========== p3: 0 reads; stage SA1'; vmcnt(4) ===========================
    if (st) {
      gload16(Xt + srcO[3][0] + ko, lds + nbo + dstO[3][0]);
      gload16(Xt + srcO[3][1] + ko, lds + nbo + dstO[3][1]);
      asm volatile("s_waitcnt vmcnt(4)" ::: "memory");   // SA0',SB0' resident
    }
    __builtin_amdgcn_s_barrier();
    __builtin_amdgcn_sched_barrier(0);
    __builtin_amdgcn_s_setprio(1);
#pragma unroll
    for (int mf = 0; mf < 4; ++mf)
#pragma unroll
      for (int nf = 0; nf < 2; ++nf) {
        acc[4 + mf][2 + nf] = __builtin_amdgcn_mfma_f32_16x16x32_bf16(aF[mf][0], cF[nf][0], acc[4 + mf][2 + nf], 0, 0, 0);
        acc[4 + mf][2 + nf] = __builtin_amdgcn_mfma_f32_16x16x32_bf16(aF[mf][1], cF[nf][1], acc[4 + mf][2 + nf], 0, 0, 0);
      }
    __builtin_amdgcn_s_setprio(0);
    __builtin_amdgcn_sched_barrier(0);
    __builtin_amdgcn_s_barrier();
    __builtin_amdgcn_sched_barrier(0);
  }
#undef RD

  // ---- epilogue (R3-verified): bt = cblk*2 + wave_m; f = i*16 + g*4 + j;
  //      n = nblk*256 + wave_n*64 + j2*16 + lr
  int bt = cblk * 2 + wave_m;
  size_t zbase = (size_t)bt * (NN * FF);
  int nb = nblk * 256 + wave_n * 64 + lr;
#pragma unroll
  for (int i = 0; i < 8; ++i) {
#pragma unroll
    for (int j2 = 0; j2 < 4; ++j2) {
      int n = nb + j2 * 16;
      int f0 = i * 16 + g * 4;
      ushort4v pk;
#pragma unroll
      for (int j = 0; j < 4; ++j) pk[j] = f2bf(acc[i][j2][j]);
      *reinterpret_cast<ushort4v*>(&Zn[zbase + (size_t)n * FF + f0]) = pk;
    }
  }
}

// ---- output GEMM: Y[bt][n][o] = sum_k sum_f Z_k[bt-k][n][f] * Wk2[k][o][f] + b
__global__ __launch_bounds__(256) void k_out(const unsigned short* __restrict__ Xbf,
                                             const unsigned short* __restrict__ Zn1,
                                             const unsigned short* __restrict__ Zn2,
                                             const unsigned short* __restrict__ Zn3,
                                             const unsigned short* __restrict__ Wk2,
                                             const float* __restrict__ bias,
                                             float* __restrict__ Y) {
  __shared__ unsigned short lA[128 * 64];
  __shared__ unsigned short lB[128 * 64];
  int bid = blockIdx.x;
  int bt = bid >> 3;
  int n0 = (bid & 7) << 7;
  int t = bt & 31;
  int tid = threadIdx.x;
  int wave = tid >> 6, lane = tid & 63;
  int wr = wave >> 1, wc = wave & 1;
  int lr = lane & 15, g = lane >> 4;

  const unsigned short* Zs[4] = {Xbf, Zn1, Zn2, Zn3};

  float4v acc[4][4];
#pragma unroll
  for (int a = 0; a < 4; ++a)
#pragma unroll
    for (int b = 0; b < 4; ++b) acc[a][b] = (float4v){0.f, 0.f, 0.f, 0.f};

  for (int s = 0; s < 8; ++s) {
    int k = s >> 1;
    if (t < k) break;
    int fh = (s & 1) * 64;
    const unsigned short* gA = Zs[k] + ((size_t)(bt - k) * NN + n0) * FF;
    const unsigned short* gB = Wk2 + k * (FF * FF);
#pragma unroll
    for (int i = 0; i < 4; ++i) {
      int id = i * 256 + tid;
      int row = id >> 3;
      int fc = (id & 7) << 3;
      int slot = (i * 256 + (tid & 192)) * 8;
      gload16(gA + (size_t)row * FF + fh + fc, &lA[slot]);
      gload16(gB + (size_t)row * FF + fh + fc, &lB[slot]);
    }
    __syncthreads();
#pragma unroll
    for (int kk = 0; kk < 2; ++kk) {
      short8 aF[4], bF[4];
#pragma unroll
      for (int mi = 0; mi < 4; ++mi)
        aF[mi] = *reinterpret_cast<const short8*>(
            &lA[(wr * 64 + mi * 16 + lr) * 64 + kk * 32 + g * 8]);
#pragma unroll
      for (int ni = 0; ni < 4; ++ni)
        bF[ni] = *reinterpret_cast<const short8*>(
            &lB[(wc * 64 + ni * 16 + lr) * 64 + kk * 32 + g * 8]);
#pragma unroll
      for (int mi = 0; mi < 4; ++mi)
#pragma unroll
        for (int ni = 0; ni < 4; ++ni)
          acc[mi][ni] = __builtin_amdgcn_mfma_f32_16x16x32_bf16(
              aF[mi], bF[ni], acc[mi][ni], 0, 0, 0);
    }
    __syncthreads();
  }

  size_t obase = (size_t)bt * (NN * FF);
#pragma unroll
  for (int mi = 0; mi < 4; ++mi) {
#pragma unroll
    for (int ni = 0; ni < 4; ++ni) {
      int nloc = n0 + wr * 64 + mi * 16 + g * 4;
      int o = wc * 64 + ni * 16 + lr;
      float bv = bias[o];
#pragma unroll
      for (int j = 0; j < 4; ++j)
        Y[obase + (size_t)(nloc + j) * FF + o] = acc[mi][ni][j] + bv;
    }
  }
}

// ---- launch ----------------------------------------------------------------

extern "C" void kernel_launch(void* const* d_in, const int* in_sizes, int n_in,
                              void* d_out, int out_size, void* d_ws, size_t ws_size,
                              hipStream_t stream) {
  const float* X = (const float*)d_in[0];
  const float* S = (const float*)d_in[1];
  const float* W = (const float*)d_in[2];
  const float* bvec = (const float*)d_in[3];
  float* Y = (float*)d_out;

  char* ws = (char*)d_ws;
  const size_t ZB = (size_t)BT * NN * FF * sizeof(unsigned short);  // 32 MiB
  const size_t SB = (size_t)1024 * 1024 * sizeof(unsigned short);   // 2 MiB
  unsigned short* Xt   = (unsigned short*)(ws + 0 * ZB);
  unsigned short* Zn1  = (unsigned short*)(ws + 1 * ZB);
  unsigned short* Zn2  = (unsigned short*)(ws + 2 * ZB);
  unsigned short* Zn3  = (unsigned short*)(ws + 3 * ZB);
  unsigned short* Xbf  = (unsigned short*)(ws + 4 * ZB);
  unsigned short* Sbf  = (unsigned short*)(ws + 5 * ZB);
  unsigned short* SbfT = (unsigned short*)(ws + 5 * ZB + 1 * SB);
  unsigned short* S2   = (unsigned short*)(ws + 5 * ZB + 2 * SB);
  unsigned short* S3   = (unsigned short*)(ws + 5 * ZB + 3 * SB);
  unsigned short* Wk2  = (unsigned short*)(ws + 5 * ZB + 4 * SB);

  k_cvt_sw<<<dim3(320), dim3(256), 0, stream>>>(S, Sbf, SbfT, W, Wk2);
  k_cvt_x<<<dim3(1024), dim3(256), 0, stream>>>(X, Xbf, Xt);

  gemm_s<<<dim3(64), dim3(256), 0, stream>>>(Sbf, SbfT, S2);   // S^2
  gemm_s<<<dim3(64), dim3(256), 0, stream>>>(S2, SbfT, S3);    // S^3

  hipError_t _e = hipFuncSetAttribute((const void*)k_chain8,
                      hipFuncAttributeMaxDynamicSharedMemorySize, 131072);
  (void)_e;
  k_chain8<<<dim3(768), dim3(512), 131072, stream>>>(Xt, Sbf, S2, S3, Zn1, Zn2, Zn3);

  k_out<<<dim3(1024), dim3(256), 0, stream>>>(Xbf, Zn1, Zn2, Zn3, Wk2, bvec, Y);
}

// Round 10
// 220.047 us; speedup vs baseline: 1.2656x; 1.0017x over previous
//
#include <hip/hip_runtime.h>
#include <stdint.h>

#define BT 128
#define NN 1024
#define FF 128

typedef __attribute__((ext_vector_type(8))) short short8;
typedef __attribute__((ext_vector_type(4))) float float4v;
typedef __attribute__((ext_vector_type(4))) unsigned short ushort4v;

__device__ __forceinline__ unsigned short f2bf(float f) {
  uint32_t u = __builtin_bit_cast(uint32_t, f);
  u += 0x7FFFu + ((u >> 16) & 1u);   // RNE
  return (unsigned short)(u >> 16);
}

__device__ __forceinline__ void gload16(const void* g, void* l) {
  __builtin_amdgcn_global_load_lds(
      (const __attribute__((address_space(1))) uint32_t*)(g),
      (__attribute__((address_space(3))) uint32_t*)(l),
      16, 0, 0);
}

// ---- fused: S -> Sbf + SbfT (blocks 0..63); W -> Wk2 (blocks 64..319) ------
__global__ __launch_bounds__(256) void k_cvt_sw(const float* __restrict__ S,
                                                unsigned short* __restrict__ Sbf,
                                                unsigned short* __restrict__ SbfT,
                                                const float* __restrict__ W,
                                                unsigned short* __restrict__ Wk2) {
  __shared__ unsigned short tile[128 * 132];
  int tid = threadIdx.x;
  if (blockIdx.x >= 64) {
    int gid = (blockIdx.x - 64) * 256 + tid;
    int k = gid >> 14, o = (gid >> 7) & 127, f = gid & 127;
    Wk2[gid] = f2bf(W[(o * 128 + f) * 4 + k]);
    return;
  }
  int r0 = ((int)blockIdx.x >> 3) << 7;
  int c0 = ((int)blockIdx.x & 7) << 7;
#pragma unroll
  for (int i = 0; i < 16; ++i) {
    int idx = i * 256 + tid;          // 4096 float4s
    int r = idx >> 5, cq = idx & 31;
    float4v v = reinterpret_cast<const float4v*>(S)[(size_t)(r0 + r) * 256 + (c0 >> 2) + cq];
    ushort4v h;
    h[0] = f2bf(v[0]); h[1] = f2bf(v[1]); h[2] = f2bf(v[2]); h[3] = f2bf(v[3]);
    *reinterpret_cast<ushort4v*>(&Sbf[(size_t)(r0 + r) * 1024 + c0 + cq * 4]) = h;
    *reinterpret_cast<ushort4v*>(&tile[r * 132 + cq * 4]) = h;
  }
  __syncthreads();
#pragma unroll
  for (int i = 0; i < 16; ++i) {
    int idx = i * 256 + tid;          // 4096 packs
    int c = idx >> 5, rq = idx & 31;
    ushort4v h;
#pragma unroll
    for (int j = 0; j < 4; ++j) h[j] = tile[(rq * 4 + j) * 132 + c];
    *reinterpret_cast<ushort4v*>(&SbfT[(size_t)(c0 + c) * 1024 + r0 + rq * 4]) = h;
  }
}

// X fp32 [bt][n][f] -> Xbf bf16 same layout, Xt bf16 [bt][f][n]
__global__ __launch_bounds__(256) void k_cvt_x(const float* __restrict__ X,
                                               unsigned short* __restrict__ Xbf,
                                               unsigned short* __restrict__ Xt) {
  __shared__ unsigned short tile[128 * 132];
  int bt = blockIdx.x >> 3;
  int n0 = (blockIdx.x & 7) << 7;
  int tid = threadIdx.x;
  size_t base = ((size_t)bt * NN + n0) * FF;
#pragma unroll
  for (int i = 0; i < 16; ++i) {
    int idx = i * 256 + tid;
    int e = idx * 4;
    int n = e >> 7, f = e & 127;
    float4v v = reinterpret_cast<const float4v*>(X + base)[idx];
    ushort4v h;
    h[0] = f2bf(v[0]); h[1] = f2bf(v[1]); h[2] = f2bf(v[2]); h[3] = f2bf(v[3]);
    reinterpret_cast<ushort4v*>(Xbf + base)[idx] = h;
    *reinterpret_cast<ushort4v*>(&tile[n * 132 + f]) = h;
  }
  __syncthreads();
  size_t tbase = (size_t)bt * (FF * NN);
#pragma unroll
  for (int i = 0; i < 64; ++i) {
    int idx = i * 256 + tid;
    int f = idx >> 7, n = idx & 127;
    Xt[tbase + (size_t)f * NN + n0 + n] = tile[n * 132 + f];
  }
}

// ---- small 1024^3 GEMM (m97 structure): C[r][c] = sum_p A[r][p]*B[c][p] ----
__global__ __launch_bounds__(256) void gemm_s(const unsigned short* __restrict__ A,
                                              const unsigned short* __restrict__ B,
                                              unsigned short* __restrict__ C) {
  __shared__ unsigned short lA[128 * 64];
  __shared__ unsigned short lB[128 * 64];
  int r0 = ((int)blockIdx.x >> 3) << 7;
  int c0 = ((int)blockIdx.x & 7) << 7;
  int tid = threadIdx.x;
  int wave = tid >> 6, lane = tid & 63;
  int wr = wave >> 1, wc = wave & 1;
  int lr = lane & 15, g = lane >> 4;

  const unsigned short* gA = A + (size_t)r0 * 1024;
  const unsigned short* gB = B + (size_t)c0 * 1024;

  float4v acc[4][4];
#pragma unroll
  for (int a = 0; a < 4; ++a)
#pragma unroll
    for (int b = 0; b < 4; ++b) acc[a][b] = (float4v){0.f, 0.f, 0.f, 0.f};

  for (int kt = 0; kt < 16; ++kt) {
    int m0 = kt * 64;
#pragma unroll
    for (int i = 0; i < 4; ++i) {
      int id = i * 256 + tid;
      int row = id >> 3;
      int mc = (id & 7) << 3;
      int slot = (i * 256 + (tid & 192)) * 8;
      gload16(gA + (size_t)row * 1024 + m0 + mc, &lA[slot]);
      gload16(gB + (size_t)row * 1024 + m0 + mc, &lB[slot]);
    }
    __syncthreads();
#pragma unroll
    for (int kk = 0; kk < 2; ++kk) {
      short8 aF[4], bF[4];
#pragma unroll
      for (int mi = 0; mi < 4; ++mi)
        aF[mi] = *reinterpret_cast<const short8*>(
            &lA[(wr * 64 + mi * 16 + lr) * 64 + kk * 32 + g * 8]);
#pragma unroll
      for (int ni = 0; ni < 4; ++ni)
        bF[ni] = *reinterpret_cast<const short8*>(
            &lB[(wc * 64 + ni * 16 + lr) * 64 + kk * 32 + g * 8]);
#pragma unroll
      for (int mi = 0; mi < 4; ++mi)
#pragma unroll
        for (int ni = 0; ni < 4; ++ni)
          acc[mi][ni] = __builtin_amdgcn_mfma_f32_16x16x32_bf16(
              aF[mi], bF[ni], acc[mi][ni], 0, 0, 0);
    }
    __syncthreads();
  }

#pragma unroll
  for (int mi = 0; mi < 4; ++mi) {
#pragma unroll
    for (int ni = 0; ni < 4; ++ni) {
      int rr = r0 + wr * 64 + mi * 16 + g * 4;
      int cc = c0 + wc * 64 + ni * 16 + lr;
#pragma unroll
      for (int j = 0; j < 4; ++j)
        C[(size_t)(rr + j) * 1024 + cc] = f2bf(acc[mi][ni][j]);
    }
  }
}

// ---- batched chain GEMM, 256^2, m201-faithful 4-phase quadrant schedule ----
// Zn_k[bt][n][f] = sum_m Xt[(bt,f)][m] * S^k[n][m]
// LDS: [256 row][64 k] row-major (128 B rows), XOR-swizzled k-segments
// (seg' = seg ^ (row&7)) via pre-swizzled coalesced global source (8 rows x
// 128 B per gload16 = 8 cache lines). Double buffer 2 x 64 KB.
// Stage-sets for kt+1 (16 KB = 2 gload16/wave): p0->SA0{rows 0-63,128-191},
// p1->SB0{0-31,64-95,128-159,192-223}, p2->SB1{+32}, p3->SA1{+64}.
// Quadrants: p0=(mh0,nh0) needs SA0+SB0, p1=(mh0,nh1) needs SB1,
// p2=(mh1,nh0) needs SA1, p3=(mh1,nh1). Counted vmcnt(4) at p0/p1/p3.
__global__ __launch_bounds__(512, 2) void k_chain8(
    const unsigned short* __restrict__ Xt,
    const unsigned short* __restrict__ S1,
    const unsigned short* __restrict__ S2,
    const unsigned short* __restrict__ S3,
    unsigned short* __restrict__ Zn1,
    unsigned short* __restrict__ Zn2,
    unsigned short* __restrict__ Zn3) {
  extern __shared__ unsigned char lds[];   // 131072 B

  int bid = blockIdx.x;
  int logical = (bid & 7) * 96 + (bid >> 3);     // 768 = 8 * 96 exact
  int cblk = logical / 12;
  int pkn = logical - cblk * 12;
  int power = pkn >> 2, nblk = pkn & 3;
  const unsigned short* Sp = (power == 0) ? S1 : ((power == 1) ? S2 : S3);
  unsigned short* Zn = (power == 0) ? Zn1 : ((power == 1) ? Zn2 : Zn3);

  int tid = threadIdx.x;
  int wave = tid >> 6, lane = tid & 63;
  int wave_m = wave >> 2, wave_n = wave & 3;
  int lr = lane & 15, g = lane >> 4;

  // ---- staging constants: sets 0=SA0, 1=SB0, 2=SB1, 3=SA1; 2 instr each.
  unsigned srcO[4][2], dstO[4][2];
#pragma unroll
  for (int j = 0; j < 2; ++j) {
    int sr0 = wave * 16 + j * 8;                       // multiple of 8
    int rbA = (sr0 & 63) + ((sr0 >> 6) << 7);          // A-set row base
    int rbB = (sr0 & 31) + ((sr0 >> 5) << 6);          // B-set row base
    int seg = lane & 7;
    int rA0 = rbA + (lane >> 3), rA1 = rA0 + 64;
    int rB0 = rbB + (lane >> 3), rB1 = rB0 + 32;
    srcO[0][j] = (unsigned)(cblk * 256 + rA0) * 1024u + (unsigned)((seg ^ (rA0 & 7)) << 3);
    srcO[3][j] = (unsigned)(cblk * 256 + rA1) * 1024u + (unsigned)((seg ^ (rA1 & 7)) << 3);
    srcO[1][j] = (unsigned)(nblk * 256 + rB0) * 1024u + (unsigned)((seg ^ (rB0 & 7)) << 3);
    srcO[2][j] = (unsigned)(nblk * 256 + rB1) * 1024u + (unsigned)((seg ^ (rB1 & 7)) << 3);
    dstO[0][j] = (unsigned)rbA * 128u;                 // wave-uniform
    dstO[3][j] = (unsigned)(rbA + 64) * 128u;
    dstO[1][j] = 32768u + (unsigned)rbB * 128u;
    dstO[2][j] = 32768u + (unsigned)(rbB + 32) * 128u;
  }

  // ---- ds_read constants (R3-verified swizzled frag reads)
  const unsigned xm = (unsigned)((lr & 7) << 4);
  const unsigned xo0 = ((unsigned)(g * 16)) ^ xm;
  const unsigned xo1 = ((unsigned)(64 + g * 16)) ^ xm;
  const unsigned aRB = (unsigned)((wave_m * 128 + lr) * 128);
  const unsigned bRB = 32768u + (unsigned)((wave_n * 64 + lr) * 128);

#define RD(OFF) (*reinterpret_cast<const short8*>(lds + (OFF)))

  float4v acc[8][4];
#pragma unroll
  for (int a = 0; a < 8; ++a)
#pragma unroll
    for (int b = 0; b < 4; ++b) acc[a][b] = (float4v){0.f, 0.f, 0.f, 0.f};

  short8 aF[4][2], bF[2][2], cF[2][2];

  // ---- prologue: stage kt0 (all sets) into buf0; drain; barrier
#pragma unroll
  for (int j = 0; j < 2; ++j) gload16(Xt + srcO[0][j], lds + dstO[0][j]);
#pragma unroll
  for (int j = 0; j < 2; ++j) gload16(Sp + srcO[1][j], lds + dstO[1][j]);
#pragma unroll
  for (int j = 0; j < 2; ++j) gload16(Sp + srcO[2][j], lds + dstO[2][j]);
#pragma unroll
  for (int j = 0; j < 2; ++j) gload16(Xt + srcO[3][j], lds + dstO[3][j]);
  asm volatile("s_waitcnt vmcnt(0)" ::: "memory");
  __builtin_amdgcn_s_barrier();

  for (int kt = 0; kt < 16; ++kt) {
    const unsigned bo = (unsigned)(kt & 1) << 16;
    const unsigned nbo = bo ^ 65536u;
    const unsigned ko = (unsigned)(kt + 1) * 64u;
    const bool st = (kt < 15);

    // ========== p0: 12 reads (aF mh0, bF nh0); stage SA0'; lgkm8; vmcnt ====
#pragma unroll
    for (int mf = 0; mf < 4; ++mf) {
      aF[mf][0] = RD(bo + aRB + (unsigned)mf * 2048u + xo0);
      aF[mf][1] = RD(bo + aRB + (unsigned)mf * 2048u + xo1);
    }
#pragma unroll
    for (int nf = 0; nf < 2; ++nf) {
      bF[nf][0] = RD(bo + bRB + (unsigned)nf * 2048u + xo0);
      bF[nf][1] = RD(bo + bRB + (unsigned)nf * 2048u + xo1);
    }
    if (st) {
      gload16(Xt + srcO[0][0] + ko, lds + nbo + dstO[0][0]);
      gload16(Xt + srcO[0][1] + ko, lds + nbo + dstO[0][1]);
      asm volatile("s_waitcnt lgkmcnt(8) vmcnt(4)" ::: "memory");
    } else {
      asm volatile("s_waitcnt lgkmcnt(8) vmcnt(2)" ::: "memory");
    }
    __builtin_amdgcn_s_barrier();
    asm volatile("s_waitcnt lgkmcnt(0)" ::: "memory");
    __builtin_amdgcn_sched_barrier(0);
    __builtin_amdgcn_s_setprio(1);
#pragma unroll
    for (int mf = 0; mf < 4; ++mf)
#pragma unroll
      for (int nf = 0; nf < 2; ++nf) {
        acc[mf][nf] = __builtin_amdgcn_mfma_f32_16x16x32_bf16(aF[mf][0], bF[nf][0], acc[mf][nf], 0, 0, 0);
        acc[mf][nf] = __builtin_amdgcn_mfma_f32_16x16x32_bf16(aF[mf][1], bF[nf][1], acc[mf][nf], 0, 0, 0);
      }
    __builtin_amdgcn_s_setprio(0);
    __builtin_amdgcn_sched_barrier(0);
    __builtin_amdgcn_s_barrier();
    __builtin_amdgcn_sched_barrier(0);

    // ========== p1: 4 reads (cF nh1); stage SB0'; vmcnt =====================
#pragma unroll
    for (int nf = 0; nf < 2; ++nf) {
      cF[nf][0] = RD(bo + bRB + 4096u + (unsigned)nf * 2048u + xo0);
      cF[nf][1] = RD(bo + bRB + 4096u + (unsigned)nf * 2048u + xo1);
    }
    if (st) {
      gload16(Sp + srcO[1][0] + ko, lds + nbo + dstO[1][0]);
      gload16(Sp + srcO[1][1] + ko, lds + nbo + dstO[1][1]);
      asm volatile("s_waitcnt vmcnt(4)" ::: "memory");
    } else {
      asm volatile("s_waitcnt vmcnt(0)" ::: "memory");
    }
    __builtin_amdgcn_s_barrier();
    asm volatile("s_waitcnt lgkmcnt(0)" ::: "memory");
    __builtin_amdgcn_sched_barrier(0);
    __builtin_amdgcn_s_setprio(1);
#pragma unroll
    for (int mf = 0; mf < 4; ++mf)
#pragma unroll
      for (int nf = 0; nf < 2; ++nf) {
        acc[mf][2 + nf] = __builtin_amdgcn_mfma_f32_16x16x32_bf16(aF[mf][0], cF[nf][0], acc[mf][2 + nf], 0, 0, 0);
        acc[mf][2 + nf] = __builtin_amdgcn_mfma_f32_16x16x32_bf16(aF[mf][1], cF[nf][1], acc[mf][2 + nf], 0, 0, 0);
      }
    __builtin_amdgcn_s_setprio(0);
    __builtin_amdgcn_sched_barrier(0);
    __builtin_amdgcn_s_barrier();
    __builtin_amdgcn_sched_barrier(0);

    // ========== p2: 8 reads (aF mh1); stage SB1'; no vm wait ================
#pragma unroll
    for (int mf = 0; mf < 4; ++mf) {
      aF[mf][0] = RD(bo + aRB + 8192u + (unsigned)mf * 2048u + xo0);
      aF[mf][1] = RD(bo + aRB + 8192u + (unsigned)mf * 2048u + xo1);
    }
    if (st) {
      gload16(Sp + srcO[2][0] + ko, lds + nbo + dstO[2][0]);
      gload16(Sp + srcO[2][1] + ko, lds + nbo + dstO[2][1]);
    }
    __builtin_amdgcn_s_barrier();
    asm volatile("s_waitcnt lgkmcnt(0)" ::: "memory");
    __builtin_amdgcn_sched_barrier(0);
    __builtin_amdgcn_s_setprio(1);
#pragma unroll
    for (int mf = 0; mf < 4; ++mf)
#pragma unroll
      for (int nf = 0; nf < 2; ++nf) {
        acc[4 + mf][nf] = __builtin_amdgcn_mfma_f32_16x16x32_bf16(aF[mf][0], bF[nf][0], acc[4 + mf][nf], 0, 0, 0);
        acc[4 + mf][nf] = __builtin_amdgcn_mfma_f32_16x16x32_bf16(aF[mf][1], bF[nf][1], acc[4 + mf][nf], 0, 0, 0);
      }
    __builtin_amdgcn_s_setprio(0);
    __builtin_amdgcn_sched_barrier(0);
    __builtin_amdgcn_s_barrier();
    __builtin_amdgcn_sched_barrier(0);

    // ========== p3: 0 reads; stage SA1'; vmcnt(4) ===========================
    if (st) {
      gload16(Xt + srcO[3][0] + ko, lds + nbo + dstO[3][0]);
      gload16(Xt + srcO[3][1] + ko, lds + nbo + dstO[3][1]);
      asm volatile("s_waitcnt vmcnt(4)" ::: "memory");   // SA0',SB0' resident
    }
    __builtin_amdgcn_s_barrier();
    __builtin_amdgcn_sched_barrier(0);
    __builtin_amdgcn_s_setprio(1);
#pragma unroll
    for (int mf = 0; mf < 4; ++mf)
#pragma unroll
      for (int nf = 0; nf < 2; ++nf) {
        acc[4 + mf][2 + nf] = __builtin_amdgcn_mfma_f32_16x16x32_bf16(aF[mf][0], cF[nf][0], acc[4 + mf][2 + nf], 0, 0, 0);
        acc[4 + mf][2 + nf] = __builtin_amdgcn_mfma_f32_16x16x32_bf16(aF[mf][1], cF[nf][1], acc[4 + mf][2 + nf], 0, 0, 0);
      }
    __builtin_amdgcn_s_setprio(0);
    __builtin_amdgcn_sched_barrier(0);
    __builtin_amdgcn_s_barrier();
    __builtin_amdgcn_sched_barrier(0);
  }
#undef RD

  // ---- epilogue (R3-verified): bt = cblk*2 + wave_m; f = i*16 + g*4 + j;
  //      n = nblk*256 + wave_n*64 + j2*16 + lr
  int bt = cblk * 2 + wave_m;
  size_t zbase = (size_t)bt * (NN * FF);
  int nb = nblk * 256 + wave_n * 64 + lr;
#pragma unroll
  for (int i = 0; i < 8; ++i) {
#pragma unroll
    for (int j2 = 0; j2 < 4; ++j2) {
      int n = nb + j2 * 16;
      int f0 = i * 16 + g * 4;
      ushort4v pk;
#pragma unroll
      for (int j = 0; j < 4; ++j) pk[j] = f2bf(acc[i][j2][j]);
      *reinterpret_cast<ushort4v*>(&Zn[zbase + (size_t)n * FF + f0]) = pk;
    }
  }
}

// ---- output GEMM: Y[bt][n][o] = sum_k sum_f Z_k[bt-k][n][f] * Wk2[k][o][f] + b
__global__ __launch_bounds__(256) void k_out(const unsigned short* __restrict__ Xbf,
                                             const unsigned short* __restrict__ Zn1,
                                             const unsigned short* __restrict__ Zn2,
                                             const unsigned short* __restrict__ Zn3,
                                             const unsigned short* __restrict__ Wk2,
                                             const float* __restrict__ bias,
                                             float* __restrict__ Y) {
  __shared__ unsigned short lA[128 * 64];
  __shared__ unsigned short lB[128 * 64];
  int bid = blockIdx.x;
  int bt = bid >> 3;
  int n0 = (bid & 7) << 7;
  int t = bt & 31;
  int tid = threadIdx.x;
  int wave = tid >> 6, lane = tid & 63;
  int wr = wave >> 1, wc = wave & 1;
  int lr = lane & 15, g = lane >> 4;

  const unsigned short* Zs[4] = {Xbf, Zn1, Zn2, Zn3};

  float4v acc[4][4];
#pragma unroll
  for (int a = 0; a < 4; ++a)
#pragma unroll
    for (int b = 0; b < 4; ++b) acc[a][b] = (float4v){0.f, 0.f, 0.f, 0.f};

  for (int s = 0; s < 8; ++s) {
    int k = s >> 1;
    if (t < k) break;
    int fh = (s & 1) * 64;
    const unsigned short* gA = Zs[k] + ((size_t)(bt - k) * NN + n0) * FF;
    const unsigned short* gB = Wk2 + k * (FF * FF);
#pragma unroll
    for (int i = 0; i < 4; ++i) {
      int id = i * 256 + tid;
      int row = id >> 3;
      int fc = (id & 7) << 3;
      int slot = (i * 256 + (tid & 192)) * 8;
      gload16(gA + (size_t)row * FF + fh + fc, &lA[slot]);
      gload16(gB + (size_t)row * FF + fh + fc, &lB[slot]);
    }
    __syncthreads();
#pragma unroll
    for (int kk = 0; kk < 2; ++kk) {
      short8 aF[4], bF[4];
#pragma unroll
      for (int mi = 0; mi < 4; ++mi)
        aF[mi] = *reinterpret_cast<const short8*>(
            &lA[(wr * 64 + mi * 16 + lr) * 64 + kk * 32 + g * 8]);
#pragma unroll
      for (int ni = 0; ni < 4; ++ni)
        bF[ni] = *reinterpret_cast<const short8*>(
            &lB[(wc * 64 + ni * 16 + lr) * 64 + kk * 32 + g * 8]);
#pragma unroll
      for (int mi = 0; mi < 4; ++mi)
#pragma unroll
        for (int ni = 0; ni < 4; ++ni)
          acc[mi][ni] = __builtin_amdgcn_mfma_f32_16x16x32_bf16(
              aF[mi], bF[ni], acc[mi][ni], 0, 0, 0);
    }
    __syncthreads();
  }

  size_t obase = (size_t)bt * (NN * FF);
#pragma unroll
  for (int mi = 0; mi < 4; ++mi) {
#pragma unroll
    for (int ni = 0; ni < 4; ++ni) {
      int nloc = n0 + wr * 64 + mi * 16 + g * 4;
      int o = wc * 64 + ni * 16 + lr;
      float bv = bias[o];
#pragma unroll
      for (int j = 0; j < 4; ++j)
        Y[obase + (size_t)(nloc + j) * FF + o] = acc[mi][ni][j] + bv;
    }
  }
}

// ---- launch ----------------------------------------------------------------

extern "C" void kernel_launch(void* const* d_in, const int* in_sizes, int n_in,
                              void* d_out, int out_size, void* d_ws, size_t ws_size,
                              hipStream_t stream) {
  const float* X = (const float*)d_in[0];
  const float* S = (const float*)d_in[1];
  const float* W = (const float*)d_in[2];
  const float* bvec = (const float*)d_in[3];
  float* Y = (float*)d_out;

  char* ws = (char*)d_ws;
  const size_t ZB = (size_t)BT * NN * FF * sizeof(unsigned short);  // 32 MiB
  const size_t SB = (size_t)1024 * 1024 * sizeof(unsigned short);   // 2 MiB
  unsigned short* Xt   = (unsigned short*)(ws + 0 * ZB);
  unsigned short* Zn1  = (unsigned short*)(ws + 1 * ZB);
  unsigned short* Zn2  = (unsigned short*)(ws + 2 * ZB);
  unsigned short* Zn3  = (unsigned short*)(ws + 3 * ZB);
  unsigned short* Xbf  = (unsigned short*)(ws + 4 * ZB);
  unsigned short* Sbf  = (unsigned short*)(ws + 5 * ZB);
  unsigned short* SbfT = (unsigned short*)(ws + 5 * ZB + 1 * SB);
  unsigned short* S2   = (unsigned short*)(ws + 5 * ZB + 2 * SB);
  unsigned short* S3   = (unsigned short*)(ws + 5 * ZB + 3 * SB);
  unsigned short* Wk2  = (unsigned short*)(ws + 5 * ZB + 4 * SB);

  k_cvt_sw<<<dim3(320), dim3(256), 0, stream>>>(S, Sbf, SbfT, W, Wk2);
  k_cvt_x<<<dim3(1024), dim3(256), 0, stream>>>(X, Xbf, Xt);

  gemm_s<<<dim3(64), dim3(256), 0, stream>>>(Sbf, SbfT, S2);   // S^2
  gemm_s<<<dim3(64), dim3(256), 0, stream>>>(S2, SbfT, S3);    // S^3

  hipError_t _e = hipFuncSetAttribute((const void*)k_chain8,
                      hipFuncAttributeMaxDynamicSharedMemorySize, 131072);
  (void)_e;
  k_chain8<<<dim3(768), dim3(512), 131072, stream>>>(Xt, Sbf, S2, S3, Zn1, Zn2, Zn3);

  k_out<<<dim3(1024), dim3(256), 0, stream>>>(Xbf, Zn1, Zn2, Zn3, Wk2, bvec, Y);
}

// Round 11
// 178.220 us; speedup vs baseline: 1.5627x; 1.2347x over previous
//
#include <hip/hip_runtime.h>
#include <stdint.h>

#define BT 128
#define NN 1024
#define FF 128

typedef __attribute__((ext_vector_type(8))) short short8;
typedef __attribute__((ext_vector_type(4))) float float4v;
typedef __attribute__((ext_vector_type(4))) unsigned short ushort4v;

__device__ __forceinline__ unsigned short f2bf(float f) {
  uint32_t u = __builtin_bit_cast(uint32_t, f);
  u += 0x7FFFu + ((u >> 16) & 1u);   // RNE
  return (unsigned short)(u >> 16);
}

__device__ __forceinline__ void gload16(const void* g, void* l) {
  __builtin_amdgcn_global_load_lds(
      (const __attribute__((address_space(1))) uint32_t*)(g),
      (__attribute__((address_space(3))) uint32_t*)(l),
      16, 0, 0);
}

// ---- converts: S->Sbf (blk 0..63), W->Wk2 [k][o][f] (64..319), zbuf (320..327)
__global__ __launch_bounds__(256) void k_cvt_sw(const float* __restrict__ S,
                                                unsigned short* __restrict__ Sbf,
                                                const float* __restrict__ W,
                                                unsigned short* __restrict__ Wk2,
                                                unsigned short* __restrict__ zbuf) {
  int tid = threadIdx.x;
  int b = blockIdx.x;
  if (b < 64) {
#pragma unroll
    for (int i = 0; i < 16; ++i) {
      int g4 = b * 4096 + i * 256 + tid;
      float4v v = reinterpret_cast<const float4v*>(S)[g4];
      ushort4v h;
      h[0] = f2bf(v[0]); h[1] = f2bf(v[1]); h[2] = f2bf(v[2]); h[3] = f2bf(v[3]);
      reinterpret_cast<ushort4v*>(Sbf)[g4] = h;
    }
  } else if (b < 320) {
    int gid = (b - 64) * 256 + tid;
    int k = gid >> 14, o = (gid >> 7) & 127, f = gid & 127;
    Wk2[gid] = f2bf(W[(o * 128 + f) * 4 + k]);
  } else {
    ushort4v z = (ushort4v){0, 0, 0, 0};
#pragma unroll
    for (int i = 0; i < 16; ++i)
      reinterpret_cast<ushort4v*>(zbuf)[(b - 320) * 4096 + i * 256 + tid] = z;
  }
}

// X fp32 [bt][n][f] -> Xbf bf16 same layout (pure streaming)
__global__ __launch_bounds__(256) void k_cvt_x(const float* __restrict__ X,
                                               unsigned short* __restrict__ Xbf) {
  int base = blockIdx.x * 1024 + threadIdx.x;   // float4 units
#pragma unroll
  for (int i = 0; i < 4; ++i) {
    int g4 = base + i * 256;
    float4v v = reinterpret_cast<const float4v*>(X)[g4];
    ushort4v h;
    h[0] = f2bf(v[0]); h[1] = f2bf(v[1]); h[2] = f2bf(v[2]); h[3] = f2bf(v[3]);
    reinterpret_cast<ushort4v*>(Xbf)[g4] = h;
  }
}

// ---- k_proj: U3[bt][o][n] = sum_f W3[o][f] * Xbf[bt][n][f]  (K=128) --------
// gemm_s-clone, ld=128; grid: bt(128) x n0(8 of 128)
__global__ __launch_bounds__(256) void k_proj(const unsigned short* __restrict__ Wk2,
                                              const unsigned short* __restrict__ Xbf,
                                              unsigned short* __restrict__ U3) {
  __shared__ unsigned short lA[128 * 64];
  __shared__ unsigned short lB[128 * 64];
  int bt = blockIdx.x >> 3;
  int n0 = (blockIdx.x & 7) << 7;
  int tid = threadIdx.x;
  int wave = tid >> 6, lane = tid & 63;
  int wr = wave >> 1, wc = wave & 1;
  int lr = lane & 15, g = lane >> 4;

  const unsigned short* gA = Wk2 + 3 * (FF * FF);            // W3 [o][f], ld 128
  const unsigned short* gB = Xbf + (size_t)bt * (NN * FF) + (size_t)n0 * FF;  // [n][f]

  float4v acc[4][4];
#pragma unroll
  for (int a = 0; a < 4; ++a)
#pragma unroll
    for (int b = 0; b < 4; ++b) acc[a][b] = (float4v){0.f, 0.f, 0.f, 0.f};

  for (int kt = 0; kt < 2; ++kt) {
    int m0 = kt * 64;
#pragma unroll
    for (int i = 0; i < 4; ++i) {
      int id = i * 256 + tid;
      int row = id >> 3;
      int mc = (id & 7) << 3;
      int slot = (i * 256 + (tid & 192)) * 8;
      gload16(gA + (size_t)row * 128 + m0 + mc, &lA[slot]);
      gload16(gB + (size_t)row * 128 + m0 + mc, &lB[slot]);
    }
    __syncthreads();
#pragma unroll
    for (int kk = 0; kk < 2; ++kk) {
      short8 aF[4], bF[4];
#pragma unroll
      for (int mi = 0; mi < 4; ++mi)
        aF[mi] = *reinterpret_cast<const short8*>(
            &lA[(wr * 64 + mi * 16 + lr) * 64 + kk * 32 + g * 8]);
#pragma unroll
      for (int ni = 0; ni < 4; ++ni)
        bF[ni] = *reinterpret_cast<const short8*>(
            &lB[(wc * 64 + ni * 16 + lr) * 64 + kk * 32 + g * 8]);
#pragma unroll
      for (int mi = 0; mi < 4; ++mi)
#pragma unroll
        for (int ni = 0; ni < 4; ++ni)
          acc[mi][ni] = __builtin_amdgcn_mfma_f32_16x16x32_bf16(
              aF[mi], bF[ni], acc[mi][ni], 0, 0, 0);
    }
    __syncthreads();
  }

  unsigned short* Uo = U3 + (size_t)bt * (NN * FF);
#pragma unroll
  for (int mi = 0; mi < 4; ++mi) {
#pragma unroll
    for (int ni = 0; ni < 4; ++ni) {
      int o = wr * 64 + mi * 16 + g * 4;
      int n = n0 + wc * 64 + ni * 16 + lr;
#pragma unroll
      for (int j = 0; j < 4; ++j)
        Uo[(size_t)(o + j) * NN + n] = f2bf(acc[mi][ni][j]);
    }
  }
}

// ---- Horner chain step: Hout[t][o][n'] = sum_n Uin[t-1][o][n]*S[n'][n]
//                                        + sum_f Wg[o][f]*Xbf[t][n'][f]  (+bias)
// S-part: R9/R10-verified 256^2 4-phase schedule, XOR-swizzled LDS, counted
// vmcnt. A rows 0-127 <- Uin[bt0-1] (zbuf when t0==0), 128-255 <- Uin[bt0].
// W-part: K=128 appended, A/B frags read global (L2-resident), same acc.
template <bool FINAL>
__global__ __launch_bounds__(512, 2) void k_chain(
    const unsigned short* __restrict__ Uin,
    const unsigned short* __restrict__ Sbf,
    const unsigned short* __restrict__ Wg,     // Wk2 + kw*16384
    const unsigned short* __restrict__ Xbf,
    const unsigned short* __restrict__ zbuf,
    unsigned short* __restrict__ Hout,
    float* __restrict__ Yout,
    const float* __restrict__ bias) {
  extern __shared__ unsigned char lds[];   // 131072 B

  int bid = blockIdx.x;
  int logical = (bid & 7) * 32 + (bid >> 3);   // 256 = 8 x 32, bijective
  int cblk = logical >> 2;                     // 0..63  (bt pair)
  int nblk = logical & 3;                      // 0..3   (n' 256-block)

  int tid = threadIdx.x;
  int wave = tid >> 6, lane = tid & 63;
  int wave_m = wave >> 2, wave_n = wave & 3;
  int lr = lane & 15, g = lane >> 4;

  const int bt0 = cblk * 2;
  const bool t0z = ((bt0 & 31) == 0);
  const unsigned short* A0 = t0z ? zbuf : (Uin + (size_t)(bt0 - 1) * (NN * FF));
  const unsigned short* A1 = Uin + (size_t)bt0 * (NN * FF);

  // ---- staging pointers: sets 0=SA0, 1=SB0, 2=SB1, 3=SA1; 2 instr each.
  const unsigned short* pS[4][2];
  unsigned dstO[4][2];
#pragma unroll
  for (int j = 0; j < 2; ++j) {
    int sr0 = wave * 16 + j * 8;
    int rbA = (sr0 & 63) + ((sr0 >> 6) << 7);
    int rbB = (sr0 & 31) + ((sr0 >> 5) << 6);
    int seg = lane & 7;
    int rA0 = rbA + (lane >> 3), rA1 = rA0 + 64;
    int rB0 = rbB + (lane >> 3), rB1 = rB0 + 32;
    pS[0][j] = (rA0 < 128 ? A0 + (size_t)rA0 * NN : A1 + (size_t)(rA0 - 128) * NN)
               + ((seg ^ (rA0 & 7)) << 3);
    pS[3][j] = (rA1 < 128 ? A0 + (size_t)rA1 * NN : A1 + (size_t)(rA1 - 128) * NN)
               + ((seg ^ (rA1 & 7)) << 3);
    pS[1][j] = Sbf + (size_t)(nblk * 256 + rB0) * NN + ((seg ^ (rB0 & 7)) << 3);
    pS[2][j] = Sbf + (size_t)(nblk * 256 + rB1) * NN + ((seg ^ (rB1 & 7)) << 3);
    dstO[0][j] = (unsigned)rbA * 128u;
    dstO[3][j] = (unsigned)(rbA + 64) * 128u;
    dstO[1][j] = 32768u + (unsigned)rbB * 128u;
    dstO[2][j] = 32768u + (unsigned)(rbB + 32) * 128u;
  }

  // ---- ds_read constants (R9-verified)
  const unsigned xm = (unsigned)((lr & 7) << 4);
  const unsigned xo0 = ((unsigned)(g * 16)) ^ xm;
  const unsigned xo1 = ((unsigned)(64 + g * 16)) ^ xm;
  const unsigned aRB = (unsigned)((wave_m * 128 + lr) * 128);
  const unsigned bRB = 32768u + (unsigned)((wave_n * 64 + lr) * 128);

#define RD(OFF) (*reinterpret_cast<const short8*>(lds + (OFF)))

  float4v acc[8][4];
#pragma unroll
  for (int a = 0; a < 8; ++a)
#pragma unroll
    for (int b = 0; b < 4; ++b) acc[a][b] = (float4v){0.f, 0.f, 0.f, 0.f};

  short8 aF[4][2], bF[2][2], cF[2][2];

  // ---- prologue: stage kt0 into buf0
#pragma unroll
  for (int s = 0; s < 4; ++s)
#pragma unroll
    for (int j = 0; j < 2; ++j) gload16(pS[s][j], lds + dstO[s][j]);
  asm volatile("s_waitcnt vmcnt(0)" ::: "memory");
  __builtin_amdgcn_s_barrier();

  for (int kt = 0; kt < 16; ++kt) {
    const unsigned bo = (unsigned)(kt & 1) << 16;
    const unsigned nbo = bo ^ 65536u;
    const unsigned ko = (unsigned)(kt + 1) * 64u;
    const bool st = (kt < 15);

    // ===== p0: 12 reads (aF mh0, bF nh0); stage SA0'; lgkm8 + vmcnt =====
#pragma unroll
    for (int mf = 0; mf < 4; ++mf) {
      aF[mf][0] = RD(bo + aRB + (unsigned)mf * 2048u + xo0);
      aF[mf][1] = RD(bo + aRB + (unsigned)mf * 2048u + xo1);
    }
#pragma unroll
    for (int nf = 0; nf < 2; ++nf) {
      bF[nf][0] = RD(bo + bRB + (unsigned)nf * 2048u + xo0);
      bF[nf][1] = RD(bo + bRB + (unsigned)nf * 2048u + xo1);
    }
    if (st) {
      gload16(pS[0][0] + ko, lds + nbo + dstO[0][0]);
      gload16(pS[0][1] + ko, lds + nbo + dstO[0][1]);
      asm volatile("s_waitcnt lgkmcnt(8) vmcnt(4)" ::: "memory");
    } else {
      asm volatile("s_waitcnt lgkmcnt(8) vmcnt(2)" ::: "memory");
    }
    __builtin_amdgcn_s_barrier();
    asm volatile("s_waitcnt lgkmcnt(0)" ::: "memory");
    __builtin_amdgcn_sched_barrier(0);
    __builtin_amdgcn_s_setprio(1);
#pragma unroll
    for (int mf = 0; mf < 4; ++mf)
#pragma unroll
      for (int nf = 0; nf < 2; ++nf) {
        acc[mf][nf] = __builtin_amdgcn_mfma_f32_16x16x32_bf16(aF[mf][0], bF[nf][0], acc[mf][nf], 0, 0, 0);
        acc[mf][nf] = __builtin_amdgcn_mfma_f32_16x16x32_bf16(aF[mf][1], bF[nf][1], acc[mf][nf], 0, 0, 0);
      }
    __builtin_amdgcn_s_setprio(0);
    __builtin_amdgcn_sched_barrier(0);
    __builtin_amdgcn_s_barrier();
    __builtin_amdgcn_sched_barrier(0);

    // ===== p1: 4 reads (cF nh1); stage SB0'; vmcnt =====
#pragma unroll
    for (int nf = 0; nf < 2; ++nf) {
      cF[nf][0] = RD(bo + bRB + 4096u + (unsigned)nf * 2048u + xo0);
      cF[nf][1] = RD(bo + bRB + 4096u + (unsigned)nf * 2048u + xo1);
    }
    if (st) {
      gload16(pS[1][0] + ko, lds + nbo + dstO[1][0]);
      gload16(pS[1][1] + ko, lds + nbo + dstO[1][1]);
      asm volatile("s_waitcnt vmcnt(4)" ::: "memory");
    } else {
      asm volatile("s_waitcnt vmcnt(0)" ::: "memory");
    }
    __builtin_amdgcn_s_barrier();
    asm volatile("s_waitcnt lgkmcnt(0)" ::: "memory");
    __builtin_amdgcn_sched_barrier(0);
    __builtin_amdgcn_s_setprio(1);
#pragma unroll
    for (int mf = 0; mf < 4; ++mf)
#pragma unroll
      for (int nf = 0; nf < 2; ++nf) {
        acc[mf][2 + nf] = __builtin_amdgcn_mfma_f32_16x16x32_bf16(aF[mf][0], cF[nf][0], acc[mf][2 + nf], 0, 0, 0);
        acc[mf][2 + nf] = __builtin_amdgcn_mfma_f32_16x16x32_bf16(aF[mf][1], cF[nf][1], acc[mf][2 + nf], 0, 0, 0);
      }
    __builtin_amdgcn_s_setprio(0);
    __builtin_amdgcn_sched_barrier(0);
    __builtin_amdgcn_s_barrier();
    __builtin_amdgcn_sched_barrier(0);

    // ===== p2: 8 reads (aF mh1); stage SB1'; no vm wait =====
#pragma unroll
    for (int mf = 0; mf < 4; ++mf) {
      aF[mf][0] = RD(bo + aRB + 8192u + (unsigned)mf * 2048u + xo0);
      aF[mf][1] = RD(bo + aRB + 8192u + (unsigned)mf * 2048u + xo1);
    }
    if (st) {
      gload16(pS[2][0] + ko, lds + nbo + dstO[2][0]);
      gload16(pS[2][1] + ko, lds + nbo + dstO[2][1]);
    }
    __builtin_amdgcn_s_barrier();
    asm volatile("s_waitcnt lgkmcnt(0)" ::: "memory");
    __builtin_amdgcn_sched_barrier(0);
    __builtin_amdgcn_s_setprio(1);
#pragma unroll
    for (int mf = 0; mf < 4; ++mf)
#pragma unroll
      for (int nf = 0; nf < 2; ++nf) {
        acc[4 + mf][nf] = __builtin_amdgcn_mfma_f32_16x16x32_bf16(aF[mf][0], bF[nf][0], acc[4 + mf][nf], 0, 0, 0);
        acc[4 + mf][nf] = __builtin_amdgcn_mfma_f32_16x16x32_bf16(aF[mf][1], bF[nf][1], acc[4 + mf][nf], 0, 0, 0);
      }
    __builtin_amdgcn_s_setprio(0);
    __builtin_amdgcn_sched_barrier(0);
    __builtin_amdgcn_s_barrier();
    __builtin_amdgcn_sched_barrier(0);

    // ===== p3: 0 reads; stage SA1'; vmcnt(4) =====
    if (st) {
      gload16(pS[3][0] + ko, lds + nbo + dstO[3][0]);
      gload16(pS[3][1] + ko, lds + nbo + dstO[3][1]);
      asm volatile("s_waitcnt vmcnt(4)" ::: "memory");
    }
    __builtin_amdgcn_s_barrier();
    __builtin_amdgcn_sched_barrier(0);
    __builtin_amdgcn_s_setprio(1);
#pragma unroll
    for (int mf = 0; mf < 4; ++mf)
#pragma unroll
      for (int nf = 0; nf < 2; ++nf) {
        acc[4 + mf][2 + nf] = __builtin_amdgcn_mfma_f32_16x16x32_bf16(aF[mf][0], cF[nf][0], acc[4 + mf][2 + nf], 0, 0, 0);
        acc[4 + mf][2 + nf] = __builtin_amdgcn_mfma_f32_16x16x32_bf16(aF[mf][1], cF[nf][1], acc[4 + mf][2 + nf], 0, 0, 0);
      }
    __builtin_amdgcn_s_setprio(0);
    __builtin_amdgcn_sched_barrier(0);
    __builtin_amdgcn_s_barrier();
    __builtin_amdgcn_sched_barrier(0);
  }
#undef RD

  // ---- W-part: acc[mf][nf] += Wg[o][f] (x) Xbf[bt][n'][f], K=128 ----------
  int bt = bt0 + wave_m;
  const unsigned short* Xb = Xbf + (size_t)bt * (NN * FF);
  const int nbase = nblk * 256 + wave_n * 64;
#pragma unroll 1
  for (int kk = 0; kk < 4; ++kk) {
    int fc = kk * 32 + g * 8;
    short8 aW[8], bW[4];
#pragma unroll
    for (int mf = 0; mf < 8; ++mf)
      aW[mf] = *reinterpret_cast<const short8*>(Wg + (size_t)(mf * 16 + lr) * FF + fc);
#pragma unroll
    for (int nf = 0; nf < 4; ++nf)
      bW[nf] = *reinterpret_cast<const short8*>(Xb + (size_t)(nbase + nf * 16 + lr) * FF + fc);
#pragma unroll
    for (int mf = 0; mf < 8; ++mf)
#pragma unroll
      for (int nf = 0; nf < 4; ++nf)
        acc[mf][nf] = __builtin_amdgcn_mfma_f32_16x16x32_bf16(aW[mf], bW[nf], acc[mf][nf], 0, 0, 0);
  }

  // ---- epilogue: D row = o (A-row), D col = n' (B-row) --------------------
  if constexpr (FINAL) {
    float* Yp = Yout + (size_t)bt * (NN * FF);
#pragma unroll
    for (int i = 0; i < 8; ++i) {
      int o0 = i * 16 + g * 4;
      float4v bv = *reinterpret_cast<const float4v*>(bias + o0);
#pragma unroll
      for (int j2 = 0; j2 < 4; ++j2) {
        int n = nbase + j2 * 16 + lr;
        float4v r = acc[i][j2] + bv;
        *reinterpret_cast<float4v*>(Yp + (size_t)n * FF + o0) = r;
      }
    }
  } else {
    unsigned short* Hp = Hout + (size_t)bt * (NN * FF);
#pragma unroll
    for (int i = 0; i < 8; ++i) {
      int o0 = i * 16 + g * 4;
#pragma unroll
      for (int j2 = 0; j2 < 4; ++j2) {
        int n = nbase + j2 * 16 + lr;
#pragma unroll
        for (int j = 0; j < 4; ++j)
          Hp[(size_t)(o0 + j) * NN + n] = f2bf(acc[i][j2][j]);
      }
    }
  }
}

// ---- launch ----------------------------------------------------------------

extern "C" void kernel_launch(void* const* d_in, const int* in_sizes, int n_in,
                              void* d_out, int out_size, void* d_ws, size_t ws_size,
                              hipStream_t stream) {
  const float* X = (const float*)d_in[0];
  const float* S = (const float*)d_in[1];
  const float* W = (const float*)d_in[2];
  const float* bvec = (const float*)d_in[3];
  float* Y = (float*)d_out;

  char* ws = (char*)d_ws;
  const size_t ZB = (size_t)BT * NN * FF * sizeof(unsigned short);  // 32 MiB
  unsigned short* Xbf = (unsigned short*)(ws + 0 * ZB);
  unsigned short* U3  = (unsigned short*)(ws + 1 * ZB);
  unsigned short* H2  = (unsigned short*)(ws + 2 * ZB);
  unsigned short* H1  = (unsigned short*)(ws + 3 * ZB);
  unsigned short* Sbf = (unsigned short*)(ws + 4 * ZB);                    // 2 MiB
  unsigned short* Wk2 = (unsigned short*)(ws + 4 * ZB + (size_t)2097152);  // 128 KiB
  unsigned short* zbf = (unsigned short*)(ws + 4 * ZB + (size_t)2097152 + 131072);  // 256 KiB

  k_cvt_sw<<<dim3(328), dim3(256), 0, stream>>>(S, Sbf, W, Wk2, zbf);
  k_cvt_x<<<dim3(4096), dim3(256), 0, stream>>>(X, Xbf);
  k_proj<<<dim3(1024), dim3(256), 0, stream>>>(Wk2, Xbf, U3);

  hipError_t e0 = hipFuncSetAttribute((const void*)k_chain<false>,
                      hipFuncAttributeMaxDynamicSharedMemorySize, 131072);
  hipError_t e1 = hipFuncSetAttribute((const void*)k_chain<true>,
                      hipFuncAttributeMaxDynamicSharedMemorySize, 131072);
  (void)e0; (void)e1;

  // H2 = S*U3[t-1] + X*W2^T
  k_chain<false><<<dim3(256), dim3(512), 131072, stream>>>(
      U3, Sbf, Wk2 + 2 * (FF * FF), Xbf, zbf, H2, nullptr, nullptr);
  // H1 = S*H2[t-1] + X*W1^T
  k_chain<false><<<dim3(256), dim3(512), 131072, stream>>>(
      H2, Sbf, Wk2 + 1 * (FF * FF), Xbf, zbf, H1, nullptr, nullptr);
  // Y = S*H1[t-1] + X*W0^T + b
  k_chain<true><<<dim3(256), dim3(512), 131072, stream>>>(
      H1, Sbf, Wk2, Xbf, zbf, nullptr, Y, bvec);
}